// Round 6
// baseline (551.287 us; speedup 1.0000x reference)
//
#include <hip/hip_runtime.h>
#include <hip/hip_bf16.h>

typedef __hip_bfloat16 bf16;

#define B_   8
#define C_   192
#define OC3  576
#define H_   128
#define W_   128
#define HW_  16384
#define HEADS_ 4
#define D_   48

typedef float f32x4 __attribute__((ext_vector_type(4)));
typedef __bf16 bf16x8 __attribute__((ext_vector_type(8)));

__device__ __forceinline__ float b2f(bf16 v) { return __bfloat162float(v); }
__device__ __forceinline__ void  stv(bf16* p, float v)  { *p = __float2bfloat16(v); }
__device__ __forceinline__ void  stv(float* p, float v) { *p = v; }

// async 16B global -> LDS (per-lane global addr; LDS dest = wave-uniform base + lane*16)
__device__ __forceinline__ void llds16(const void* g, void* l) {
    __builtin_amdgcn_global_load_lds(
        (const __attribute__((address_space(1))) unsigned int*)g,
        (__attribute__((address_space(3))) unsigned int*)l, 16, 0, 0);
}

// ---------------------------------------------------------------------------
// Convert qkv_w (576x192) fp32 -> bf16 (rows padded to 640; pad rows = finite
// poison, masked at GEMM store). grid 576 x 192 threads.
// ---------------------------------------------------------------------------
__global__ void cvt_w(const float* __restrict__ qkv_w, __bf16* __restrict__ Wq) {
    const int row = blockIdx.x, c = threadIdx.x;
    Wq[row * C_ + c] = (__bf16)qkv_w[row * C_ + c];
}

// ---------------------------------------------------------------------------
// Transpose-convert x[b][c][p] fp32 -> Xt[b][p][c] bf16.
// ---------------------------------------------------------------------------
__global__ void tx_cvt(const float* __restrict__ x, __bf16* __restrict__ Xt) {
    const int p0 = blockIdx.x * 128;
    const int b  = blockIdx.z;
    __shared__ __bf16 LT[128 * 196];

    for (int idx = threadIdx.x; idx < C_ * 128; idx += 256) {
        int c = idx >> 7, pp = idx & 127;
        LT[pp * 196 + c] = (__bf16)x[((size_t)b * C_ + c) * HW_ + p0 + pp];
    }
    __syncthreads();
    for (int idx = threadIdx.x; idx < 128 * 48; idx += 256) {
        int pp = idx / 48, c4 = idx % 48;
        *(uint2*)&Xt[((size_t)b * HW_ + p0 + pp) * C_ + c4 * 4] =
            *(const uint2*)&LT[pp * 196 + c4 * 4];
    }
}

// ---------------------------------------------------------------------------
// Transpose v-part of qkv2: vt[b][p][c] (c=0..191 => channel 384+c) bf16.
// ---------------------------------------------------------------------------
__global__ void vtx(const bf16* __restrict__ qkv2, __bf16* __restrict__ vt) {
    const int p0 = blockIdx.x * 128;
    const int b  = blockIdx.z;
    const bf16* vb = qkv2 + ((size_t)b * OC3 + 384) * HW_;
    __shared__ __bf16 LT[128 * 200];

    for (int idx = threadIdx.x; idx < C_ * 128; idx += 256) {
        int c = idx >> 7, pp = idx & 127;
        LT[pp * 200 + c] = *(const __bf16*)&vb[(size_t)c * HW_ + p0 + pp];
    }
    __syncthreads();
    for (int idx = threadIdx.x; idx < 128 * 48; idx += 256) {
        int pp = idx / 48, c4 = idx % 48;
        *(uint2*)&vt[((size_t)b * HW_ + p0 + pp) * C_ + c4 * 4] =
            *(const uint2*)&LT[pp * 200 + c4 * 4];
    }
}

// ---------------------------------------------------------------------------
// Direct-MFMA GEMM, K=192, no LDS, no barriers.
// Y[b][o][p] = sum_k A[o][k] * Xt[b][p][k] + bias[o]
// grid (HW/128, O_pad/128, B), 256 thr = 4 waves in 2x2 (each 64o x 64p).
// Fragments loaded straight from global: per row the 4 qd-lanes cover 64
// contiguous bytes; W tiles are L2-resident; Xt re-reads absorbed by L2/L3.
// ---------------------------------------------------------------------------
template<typename TOut>
__global__ __launch_bounds__(256) void gemm_direct(
        const __bf16* __restrict__ Wp, const __bf16* __restrict__ Xt,
        const float* __restrict__ bias, TOut* __restrict__ Y,
        const int O, const size_t a_bstride) {
    const int K = C_;
    const int tid = threadIdx.x, wid = tid >> 6, lane = tid & 63;
    const int lm = lane & 15, qd = lane >> 4;
    const int p0 = blockIdx.x * 128, o0 = blockIdx.y * 128, b = blockIdx.z;
    const int wo0 = (wid >> 1) * 64, wn0 = (wid & 1) * 64;

    const __bf16* Arow[4];
    const __bf16* Brow[4];
#pragma unroll
    for (int i = 0; i < 4; ++i)
        Arow[i] = Wp + a_bstride * b + (size_t)(o0 + wo0 + i * 16 + lm) * K + qd * 8;
#pragma unroll
    for (int j = 0; j < 4; ++j)
        Brow[j] = Xt + ((size_t)b * HW_ + p0 + wn0 + j * 16 + lm) * K + qd * 8;

    f32x4 acc[4][4] = {};
#pragma unroll
    for (int k0 = 0; k0 < 192; k0 += 32) {
        bf16x8 af[4], bfr[4];
#pragma unroll
        for (int i = 0; i < 4; ++i) af[i]  = *(const bf16x8*)(Arow[i] + k0);
#pragma unroll
        for (int j = 0; j < 4; ++j) bfr[j] = *(const bf16x8*)(Brow[j] + k0);
#pragma unroll
        for (int i = 0; i < 4; ++i)
#pragma unroll
            for (int j = 0; j < 4; ++j)
                acc[i][j] = __builtin_amdgcn_mfma_f32_16x16x32_bf16(
                    af[i], bfr[j], acc[i][j], 0, 0, 0);
    }

    TOut* Yb = Y + (size_t)b * O * HW_;
#pragma unroll
    for (int i = 0; i < 4; ++i) {
#pragma unroll
        for (int j = 0; j < 4; ++j) {
            const int p = p0 + wn0 + j * 16 + lm;
#pragma unroll
            for (int r = 0; r < 4; ++r) {
                const int o = o0 + wo0 + i * 16 + qd * 4 + r;
                if (o < O)
                    stv(&Yb[(size_t)o * HW_ + p], acc[i][j][r] + bias[o]);
            }
        }
    }
}

// ---------------------------------------------------------------------------
// depthwise 3x3 + fused sum-of-squares (for q,k L2 norms).
// grid (ch=576, b=8), block 256. Whole 128x128 plane staged in LDS (32 KB).
// ---------------------------------------------------------------------------
__device__ __forceinline__ void dw_load_row(const __bf16* plane, int yy, int x0,
                                            float* r) {
    if (yy < 0 || yy > 127) {
#pragma unroll
        for (int i = 0; i < 10; ++i) r[i] = 0.f;
        return;
    }
    const __bf16* row = plane + yy * 128;
    bf16x8 v = *(const bf16x8*)(row + x0);
    r[0] = (x0 > 0) ? (float)row[x0 - 1] : 0.f;
#pragma unroll
    for (int i = 0; i < 8; ++i) r[1 + i] = (float)v[i];
    r[9] = (x0 + 8 < 128) ? (float)row[x0 + 8] : 0.f;
}

__global__ __launch_bounds__(256) void dwconv_fused(
        const bf16* __restrict__ in, const float* __restrict__ w9,
        const float* __restrict__ bias, bf16* __restrict__ out,
        float* __restrict__ sumsq) {
    const int ch = blockIdx.x;
    const int b  = blockIdx.y;
    const int tid = threadIdx.x;
    const char* ib = (const char*)(in + ((size_t)b * OC3 + ch) * HW_);

    __shared__ __bf16 plane[16384];
    __shared__ float red[256];

    {
        const int wid = tid >> 6, lane = tid & 63;
        char* lbase = (char*)plane + wid * 8192;
        const char* gbase = ib + wid * 8192;
#pragma unroll
        for (int i = 0; i < 8; ++i)
            llds16(gbase + i * 1024 + lane * 16, lbase + i * 1024);
    }

    float wv[9];
#pragma unroll
    for (int i = 0; i < 9; ++i) wv[i] = w9[ch * 9 + i];
    const float bi = bias[ch];

    __syncthreads();

    const int x0 = (tid & 15) * 8;
    const int y0 = (tid >> 4) * 8;
    bf16* ob = out + ((size_t)b * OC3 + ch) * HW_;

    float r0[10], r1[10], r2[10];
    dw_load_row(plane, y0 - 1, x0, r0);
    dw_load_row(plane, y0,     x0, r1);

    float ss = 0.f;
#pragma unroll
    for (int yi = 0; yi < 8; ++yi) {
        dw_load_row(plane, y0 + yi + 1, x0, r2);
        bf16x8 st;
#pragma unroll
        for (int xx = 0; xx < 8; ++xx) {
            float o = bi;
#pragma unroll
            for (int dx = 0; dx < 3; ++dx) {
                o += wv[0 + dx] * r0[xx + dx];
                o += wv[3 + dx] * r1[xx + dx];
                o += wv[6 + dx] * r2[xx + dx];
            }
            ss += o * o;
            st[xx] = (__bf16)o;
        }
        *(bf16x8*)(ob + (y0 + yi) * 128 + x0) = st;
#pragma unroll
        for (int i = 0; i < 10; ++i) { r0[i] = r1[i]; r1[i] = r2[i]; }
    }

    red[tid] = ss;
    __syncthreads();
    for (int stx = 128; stx > 0; stx >>= 1) {
        if (tid < stx) red[tid] += red[tid + stx];
        __syncthreads();
    }
    if (tid == 0) sumsq[b * OC3 + ch] = red[0];
}

// ---------------------------------------------------------------------------
// Direct-MFMA QK^T partials, no LDS staging, no barriers in the n-loop.
// S_part[slice][i][j] = sum_{n in 512-slice} q[i,n]*k[j,n]
// grid (32, HEADS, B), 256 thr; waves split each 128-chunk (kw0 = wid*32).
// Cross-wave reduce in LDS at the end.
// ---------------------------------------------------------------------------
__global__ __launch_bounds__(256) void qk_direct(const bf16* __restrict__ qkv2,
                                                 float* __restrict__ Spart) {
    const int slice = blockIdx.x, h = blockIdx.y, b = blockIdx.z;
    const __bf16* qb = (const __bf16*)(qkv2 + ((size_t)b * OC3 + h * D_) * HW_);
    const __bf16* kb = (const __bf16*)(qkv2 + ((size_t)b * OC3 + 192 + h * D_) * HW_);

    const int tid = threadIdx.x, wid = tid >> 6, lane = tid & 63;
    const int lm = lane & 15, qd = lane >> 4;
    const int kofs = wid * 32 + qd * 8;

    __shared__ float red[4 * 2304];

    f32x4 acc[3][3] = {};

#pragma unroll
    for (int sub = 0; sub < 4; ++sub) {
        const int n0 = slice * 512 + sub * 128 + kofs;
        bf16x8 af[3], bfr[3];
#pragma unroll
        for (int i = 0; i < 3; ++i)
            af[i]  = *(const bf16x8*)(qb + (size_t)(i * 16 + lm) * HW_ + n0);
#pragma unroll
        for (int j = 0; j < 3; ++j)
            bfr[j] = *(const bf16x8*)(kb + (size_t)(j * 16 + lm) * HW_ + n0);
#pragma unroll
        for (int i = 0; i < 3; ++i)
#pragma unroll
            for (int j = 0; j < 3; ++j)
                acc[i][j] = __builtin_amdgcn_mfma_f32_16x16x32_bf16(
                    af[i], bfr[j], acc[i][j], 0, 0, 0);
    }

    float* wb = red + wid * 2304;
#pragma unroll
    for (int i = 0; i < 3; ++i)
#pragma unroll
        for (int j = 0; j < 3; ++j)
#pragma unroll
            for (int r = 0; r < 4; ++r)
                wb[(i * 16 + qd * 4 + r) * 48 + j * 16 + lm] = acc[i][j][r];
    __syncthreads();

    float* outp = Spart + ((size_t)((b * HEADS_ + h) * 32 + slice)) * 2304;
    for (int t = tid; t < 2304; t += 256)
        outp[t] = red[t] + red[2304 + t] + red[4608 + t] + red[6912 + t];
}

// ---------------------------------------------------------------------------
// Collapse 32 slice-partials: Sred[bh][t] = sum_sl Spart[bh][sl][t].
// grid 288 x 256.
// ---------------------------------------------------------------------------
__global__ void sreduce(const float* __restrict__ Spart, float* __restrict__ Sred) {
    const int idx = blockIdx.x * 256 + threadIdx.x;   // 32*2304 = 73728
    const int bh = idx / 2304, t = idx % 2304;
    const float* p = Spart + (size_t)bh * 32 * 2304 + t;
    float s = 0.f;
#pragma unroll 8
    for (int sl = 0; sl < 32; ++sl) s += p[sl * 2304];
    Sred[idx] = s;
}

// ---------------------------------------------------------------------------
// apply norms (from fused sumsq) + temperature, softmax over j.
// ---------------------------------------------------------------------------
__global__ void softmax48(const float* __restrict__ Sred, const float* __restrict__ sumsq,
                          const float* __restrict__ temp, float* __restrict__ A) {
    const int h = blockIdx.x, b = blockIdx.y;
    const int i = threadIdx.x;
    if (i >= 48) return;
    const float* sq = sumsq + b * OC3 + h * D_;
    const float* sk = sumsq + b * OC3 + 192 + h * D_;
    const float t = temp[h];
    const float* Sp = Sred + (size_t)(b * HEADS_ + h) * 2304;

    const float rqi = 1.0f / fmaxf(sqrtf(sq[i]), 1e-12f);

    float s[48];
#pragma unroll
    for (int j = 0; j < 48; ++j)
        s[j] = Sp[i * 48 + j] * rqi * (1.0f / fmaxf(sqrtf(sk[j]), 1e-12f)) * t;
    float m = -1e30f;
#pragma unroll
    for (int j = 0; j < 48; ++j) m = fmaxf(m, s[j]);
    float sum = 0.f;
#pragma unroll
    for (int j = 0; j < 48; ++j) { s[j] = expf(s[j] - m); sum += s[j]; }
    float inv = 1.0f / sum;
    float* Ao = A + ((size_t)(b * HEADS_ + h) * 48 + i) * 48;
#pragma unroll
    for (int j = 0; j < 48; ++j) Ao[j] = s[j] * inv;
}

// ---------------------------------------------------------------------------
// Wf[b][o][c'] = sum_i proj_w[o][h*48+i] * A[b,h][i][j]   (c' = h*48+j)
// ---------------------------------------------------------------------------
__global__ void wfuse(const float* __restrict__ proj_w, const float* __restrict__ A,
                      __bf16* __restrict__ Wf) {
    const int o = blockIdx.x, b = blockIdx.y;
    const int cp = threadIdx.x;
    const int h = cp / 48, j = cp % 48;
    const float* wrow = proj_w + o * C_ + h * D_;
    const float* Ah = A + (size_t)(b * HEADS_ + h) * 2304;
    float s = 0.f;
#pragma unroll
    for (int i = 0; i < 48; ++i) s += wrow[i] * Ah[i * 48 + j];
    Wf[((size_t)b * 256 + o) * C_ + cp] = (__bf16)s;
}

// ---------------------------------------------------------------------------
extern "C" void kernel_launch(void* const* d_in, const int* in_sizes, int n_in,
                              void* d_out, int out_size, void* d_ws, size_t ws_size,
                              hipStream_t stream) {
    const float* x      = (const float*)d_in[0];
    const float* qkv_w  = (const float*)d_in[1];
    const float* qkv_b  = (const float*)d_in[2];
    const float* dw_w   = (const float*)d_in[3];
    const float* dw_b   = (const float*)d_in[4];
    const float* temp   = (const float*)d_in[5];
    const float* proj_w = (const float*)d_in[6];
    const float* proj_b = (const float*)d_in[7];
    float* out = (float*)d_out;

    char* ws = (char*)d_ws;
    const size_t XT_BYTES  = (size_t)B_ * HW_ * C_ * 2;      // 50,331,648
    const size_t WQ_BYTES  = 640 * C_ * 2;                   // 245,760 (padded)
    const size_t WF_BYTES  = (size_t)B_ * 256 * C_ * 2;      // 786,432 (padded)
    const size_t QKV_BYTES = (size_t)B_ * OC3 * HW_ * 2;     // 150,994,944

    size_t off = 0;
    __bf16* Xt    = (__bf16*)(ws + off); off += XT_BYTES;    // later reused as vt
    __bf16* Wq    = (__bf16*)(ws + off); off += WQ_BYTES;
    __bf16* Wf    = (__bf16*)(ws + off); off += WF_BYTES;
    bf16*   bufA  = (bf16*)(ws + off);   off += QKV_BYTES;   // qkv after 1x1
    bf16*   bufB  = (bf16*)(ws + off);   off += QKV_BYTES;   // qkv after dwconv
    float*  sumsq = (float*)(ws + off);  off += OC3 * B_ * 4;
    float*  Spart = (float*)(ws + off);  off += (size_t)32 * 2304 * 4 * 32; // 9.4 MB
    float*  Sred  = (float*)(ws + off);  off += 294912;
    float*  Attn  = (float*)(ws + off);  off += 294912;
    __bf16* vt    = Xt;  // Xt dead after qkv GEMM

    cvt_w<<<dim3(OC3), 192, 0, stream>>>(qkv_w, Wq);

    tx_cvt<<<dim3(HW_ / 128, 1, B_), 256, 0, stream>>>(x, Xt);

    gemm_direct<bf16><<<dim3(HW_ / 128, 5, B_), 256, 0, stream>>>(
        Wq, Xt, qkv_b, bufA, OC3, 0);

    dwconv_fused<<<dim3(OC3, B_), 256, 0, stream>>>(bufA, dw_w, dw_b, bufB, sumsq);

    qk_direct<<<dim3(32, HEADS_, B_), 256, 0, stream>>>(bufB, Spart);

    sreduce<<<dim3(288), 256, 0, stream>>>(Spart, Sred);

    softmax48<<<dim3(HEADS_, B_), 64, 0, stream>>>(Sred, sumsq, temp, Attn);

    vtx<<<dim3(HW_ / 128, 1, B_), 256, 0, stream>>>(bufB, vt);

    wfuse<<<dim3(C_, B_), 192, 0, stream>>>(proj_w, Attn, Wf);

    gemm_direct<float><<<dim3(HW_ / 128, 2, B_), 256, 0, stream>>>(
        Wf, vt, proj_b, out, C_, (size_t)256 * C_);
}